// Round 1
// baseline (881.881 us; speedup 1.0000x reference)
//
#include <hip/hip_runtime.h>
#include <hip/hip_bf16.h>

#define BB    64
#define DD    1024
#define HH    16
#define LL    4101          // 1 + 4 + 4096
#define NCH   8
#define CHUNK 513           // ceil(4101/8)
#define SCALE 0.125f        // 1/sqrt(64)
#define LN_EPS 1e-5f

// workspace layout (float offsets)
#define WS_QVEC   0                         // 1024
#define WS_U      1024                      // 16*1024
#define WS_C      17408                     // 16
#define WS_PL     17424                     // 64*8*16 = 8192
#define WS_PS     26624                     // 64*8*16*1024 = 8388608
#define WS_SBAR   (26624 + 8388608)         // 64*16*1024 = 1048576
#define WS_CTX    (WS_SBAR + 1048576)       // 65536
#define WS_POOLED (WS_CTX + 65536)          // 65536
// total ~9.6M floats = 38.4 MB

// ---------------- prep kernels ----------------
__global__ void k_qvec(const float* __restrict__ query, const float* __restrict__ Wq,
                       const float* __restrict__ bq, float* __restrict__ qvec) {
    int j = blockIdx.x; int lane = threadIdx.x;          // 64 threads
    const float4* wr = reinterpret_cast<const float4*>(Wq + (size_t)j * DD);
    const float4* qr = reinterpret_cast<const float4*>(query);
    float s = 0.f;
#pragma unroll
    for (int k = 0; k < 4; ++k) {
        float4 a = wr[k * 64 + lane];
        float4 q = qr[k * 64 + lane];
        s += a.x * q.x + a.y * q.y + a.z * q.z + a.w * q.w;
    }
#pragma unroll
    for (int m = 1; m < 64; m <<= 1) s += __shfl_xor(s, m, 64);
    if (lane == 0) qvec[j] = s + bq[j];
}

__global__ void k_u(const float* __restrict__ Wk, const float* __restrict__ qvec,
                    float* __restrict__ u) {
    int h = blockIdx.x >> 2;
    int d = ((blockIdx.x & 3) << 8) + threadIdx.x;       // 256 threads
    const float* wcol = Wk + (size_t)(h * 64) * DD + d;
    const float* qv = qvec + h * 64;
    float s = 0.f;
#pragma unroll 8
    for (int i = 0; i < 64; ++i) s += wcol[(size_t)i * DD] * qv[i];
    u[h * DD + d] = s * SCALE;
}

__global__ void k_c(const float* __restrict__ qvec, const float* __restrict__ bk,
                    float* __restrict__ cv) {
    int h = threadIdx.x;
    if (h < HH) {
        float s = 0.f;
        for (int i = 0; i < 64; ++i) s += qvec[h * 64 + i] * bk[h * 64 + i];
        cv[h] = s * SCALE;
    }
}

// ---------------- fused main pass ----------------
// grid = B*NCH = 512 blocks, 256 threads (4 waves). Wave w: LN-producer for
// row (4t+w) of the tile, consumer for heads 4w..4w+3 over all 4 tile rows.
__global__ __launch_bounds__(256, 2) void k_main(
    const float* __restrict__ cls, const float* __restrict__ sto,
    const float* __restrict__ pat,
    const float* __restrict__ g, const float* __restrict__ bln,
    const float* __restrict__ uvec, const float* __restrict__ cv,
    float* __restrict__ ps, float* __restrict__ pl) {
    int blk = blockIdx.x;
    int b   = blk >> 3;
    int ch  = blk & 7;
    int row0 = ch * CHUNK;
    int rows = LL - row0; if (rows > CHUNK) rows = CHUNK;
    int tid = threadIdx.x, w = tid >> 6, lane = tid & 63;

    __shared__ float4 kvs[4 * 256];          // 4 rows x 256 float4 units (swizzled)
    __shared__ float gs[DD], bs[DD];
    for (int i = tid; i < DD; i += 256) { gs[i] = g[i]; bs[i] = bln[i]; }

    // per-thread u fragments: heads 4w+e, d-slice lane*16..lane*16+15
    float ur[4][16];
    float cr[4];
#pragma unroll
    for (int e = 0; e < 4; ++e) {
        int h = 4 * w + e;
        const float4* up = reinterpret_cast<const float4*>(uvec + (size_t)h * DD + lane * 16);
#pragma unroll
        for (int it = 0; it < 4; ++it) {
            float4 v = up[it];
            ur[e][4 * it + 0] = v.x; ur[e][4 * it + 1] = v.y;
            ur[e][4 * it + 2] = v.z; ur[e][4 * it + 3] = v.w;
        }
        cr[e] = cv[h];
    }
    float acc[4][16];
#pragma unroll
    for (int e = 0; e < 4; ++e)
#pragma unroll
        for (int i = 0; i < 16; ++i) acc[e][i] = 0.f;
    float lacc[4] = {0.f, 0.f, 0.f, 0.f};

    __syncthreads();

    int nt = (rows + 3) >> 2;
    for (int t = 0; t < nt; ++t) {
        // ---- Phase A: LN one row per wave, write swizzled kv to LDS ----
        int r = 4 * t + w;
        bool valid = r < rows;                 // wave-uniform
        float x[16];
        float mean = 0.f, rstd = 0.f;
        if (valid) {
            int gr = row0 + r;
            const float* src;
            if (gr == 0)       src = cls + (size_t)b * DD;
            else if (gr <= 4)  src = sto + ((size_t)b * 4 + (gr - 1)) * DD;
            else               src = pat + ((size_t)b * 4096 + (gr - 5)) * DD;
            const float4* s4 = reinterpret_cast<const float4*>(src);
            float s1 = 0.f, s2 = 0.f;
#pragma unroll
            for (int j = 0; j < 4; ++j) {
                float4 v = s4[j * 64 + lane];
                x[4 * j + 0] = v.x; x[4 * j + 1] = v.y;
                x[4 * j + 2] = v.z; x[4 * j + 3] = v.w;
                s1 += v.x + v.y + v.z + v.w;
                s2 += v.x * v.x + v.y * v.y + v.z * v.z + v.w * v.w;
            }
#pragma unroll
            for (int m = 1; m < 64; m <<= 1) {
                s1 += __shfl_xor(s1, m, 64);
                s2 += __shfl_xor(s2, m, 64);
            }
            mean = s1 * (1.f / 1024.f);
            float var = s2 * (1.f / 1024.f) - mean * mean;
            rstd = rsqrtf(var + LN_EPS);
        }
#pragma unroll
        for (int j = 0; j < 4; ++j) {
            int u0  = 64 * j + lane;
            int swz = u0 ^ ((u0 >> 3) & 7);
            float4 o;
            if (valid) {
                int d0 = 4 * u0;
                o.x = (x[4 * j + 0] - mean) * rstd * gs[d0 + 0] + bs[d0 + 0];
                o.y = (x[4 * j + 1] - mean) * rstd * gs[d0 + 1] + bs[d0 + 1];
                o.z = (x[4 * j + 2] - mean) * rstd * gs[d0 + 2] + bs[d0 + 2];
                o.w = (x[4 * j + 3] - mean) * rstd * gs[d0 + 3] + bs[d0 + 3];
            } else {
                o = make_float4(0.f, 0.f, 0.f, 0.f);
            }
            kvs[w * 256 + swz] = o;
        }
        __syncthreads();

        // ---- Phase B: scores + exp + weighted accumulate ----
#pragma unroll
        for (int r4 = 0; r4 < 4; ++r4) {
            bool rv = (4 * t + r4) < rows;     // block-uniform
            float4 kf[4];
            float part[4] = {0.f, 0.f, 0.f, 0.f};
#pragma unroll
            for (int it = 0; it < 4; ++it) {
                int u0  = 4 * lane + it;
                int swz = u0 ^ ((u0 >> 3) & 7);
                kf[it] = kvs[r4 * 256 + swz];
#pragma unroll
                for (int e = 0; e < 4; ++e) {
                    part[e] += kf[it].x * ur[e][4 * it + 0]
                             + kf[it].y * ur[e][4 * it + 1]
                             + kf[it].z * ur[e][4 * it + 2]
                             + kf[it].w * ur[e][4 * it + 3];
                }
            }
#pragma unroll
            for (int e = 0; e < 4; ++e)
#pragma unroll
                for (int m = 1; m < 64; m <<= 1)
                    part[e] += __shfl_xor(part[e], m, 64);
            float p[4];
#pragma unroll
            for (int e = 0; e < 4; ++e) {
                p[e] = rv ? __expf(part[e] + cr[e]) : 0.f;   // shift-0 softmax: |score|<<1
                lacc[e] += p[e];
            }
#pragma unroll
            for (int it = 0; it < 4; ++it)
#pragma unroll
                for (int e = 0; e < 4; ++e) {
                    acc[e][4 * it + 0] += p[e] * kf[it].x;
                    acc[e][4 * it + 1] += p[e] * kf[it].y;
                    acc[e][4 * it + 2] += p[e] * kf[it].z;
                    acc[e][4 * it + 3] += p[e] * kf[it].w;
                }
        }
        __syncthreads();
    }

    // write partials
    size_t base = ((size_t)(b * NCH + ch) * HH) << 10;
#pragma unroll
    for (int e = 0; e < 4; ++e) {
        int h = 4 * w + e;
        float4* dst = reinterpret_cast<float4*>(ps + base + ((size_t)h << 10) + lane * 16);
#pragma unroll
        for (int it = 0; it < 4; ++it)
            dst[it] = make_float4(acc[e][4 * it + 0], acc[e][4 * it + 1],
                                  acc[e][4 * it + 2], acc[e][4 * it + 3]);
    }
    if (lane == 0) {
#pragma unroll
        for (int e = 0; e < 4; ++e)
            pl[(b * NCH + ch) * HH + 4 * w + e] = lacc[e];
    }
}

// ---------------- combine partials ----------------
__global__ void k_comb(const float* __restrict__ ps, const float* __restrict__ pl,
                       float* __restrict__ sbar) {
    int blk = blockIdx.x; int b = blk >> 4; int h = blk & 15; int tid = threadIdx.x;
    float lt = 0.f;
#pragma unroll
    for (int ch = 0; ch < NCH; ++ch) lt += pl[(b * NCH + ch) * HH + h];
    float inv = 1.f / lt;
    float4 s = make_float4(0.f, 0.f, 0.f, 0.f);
#pragma unroll
    for (int ch = 0; ch < NCH; ++ch) {
        const float4* p4 = reinterpret_cast<const float4*>(
            ps + (((size_t)(b * NCH + ch) * HH + h) << 10));
        float4 v = p4[tid];
        s.x += v.x; s.y += v.y; s.z += v.z; s.w += v.w;
    }
    float4* o = reinterpret_cast<float4*>(sbar + (((size_t)(b * HH) + h) << 10));
    o[tid] = make_float4(s.x * inv, s.y * inv, s.z * inv, s.w * inv);
}

// ---------------- ctx = Wv_h * sbar + bv ----------------
__global__ void k_ctx(const float* __restrict__ Wv, const float* __restrict__ bv,
                      const float* __restrict__ sbar, float* __restrict__ ctx) {
    int j = blockIdx.x; int h = j >> 6;
    int w = threadIdx.x >> 6, lane = threadIdx.x & 63;
    const float4* wr = reinterpret_cast<const float4*>(Wv + (size_t)j * DD);
    float4 wv[4];
#pragma unroll
    for (int k = 0; k < 4; ++k) wv[k] = wr[k * 64 + lane];
    float bvj = bv[j];
    for (int bb2 = w * 16; bb2 < w * 16 + 16; ++bb2) {
        const float4* sr = reinterpret_cast<const float4*>(
            sbar + (((size_t)(bb2 * HH) + h) << 10));
        float s = 0.f;
#pragma unroll
        for (int k = 0; k < 4; ++k) {
            float4 v = sr[k * 64 + lane];
            s += wv[k].x * v.x + wv[k].y * v.y + wv[k].z * v.z + wv[k].w * v.w;
        }
#pragma unroll
        for (int m = 1; m < 64; m <<= 1) s += __shfl_xor(s, m, 64);
        if (lane == 0) ctx[(size_t)bb2 * DD + j] = s + bvj;
    }
}

// ---------------- pooled = Wo * ctx + bo ----------------
__global__ void k_pool(const float* __restrict__ Wo, const float* __restrict__ bo,
                       const float* __restrict__ ctx, float* __restrict__ pooled) {
    int j = blockIdx.x;
    int w = threadIdx.x >> 6, lane = threadIdx.x & 63;
    const float4* wr = reinterpret_cast<const float4*>(Wo + (size_t)j * DD);
    float4 wv[4];
#pragma unroll
    for (int k = 0; k < 4; ++k) wv[k] = wr[k * 64 + lane];
    float boj = bo[j];
    for (int bb2 = w * 16; bb2 < w * 16 + 16; ++bb2) {
        const float4* cr4 = reinterpret_cast<const float4*>(ctx + (size_t)bb2 * DD);
        float s = 0.f;
#pragma unroll
        for (int k = 0; k < 4; ++k) {
            float4 v = cr4[k * 64 + lane];
            s += wv[k].x * v.x + wv[k].y * v.y + wv[k].z * v.z + wv[k].w * v.w;
        }
#pragma unroll
        for (int m = 1; m < 64; m <<= 1) s += __shfl_xor(s, m, 64);
        if (lane == 0) pooled[(size_t)bb2 * DD + j] = s + boj;
    }
}

// ---------------- final LN + classifier head ----------------
__global__ void k_head(const float* __restrict__ pooled, const float* __restrict__ g2,
                       const float* __restrict__ b2, const float* __restrict__ Wp,
                       const float* __restrict__ bp, float* __restrict__ out) {
    int b = blockIdx.x; int tid = threadIdx.x;
    __shared__ float pln[DD];
    __shared__ float red[8];
    const float4* pr = reinterpret_cast<const float4*>(pooled + (size_t)b * DD);
    float4 v = pr[tid];
    float s1 = v.x + v.y + v.z + v.w;
    float s2 = v.x * v.x + v.y * v.y + v.z * v.z + v.w * v.w;
#pragma unroll
    for (int m = 1; m < 64; m <<= 1) { s1 += __shfl_xor(s1, m, 64); s2 += __shfl_xor(s2, m, 64); }
    int w = tid >> 6, lane = tid & 63;
    if (lane == 0) { red[2 * w] = s1; red[2 * w + 1] = s2; }
    __syncthreads();
    s1 = red[0] + red[2] + red[4] + red[6];
    s2 = red[1] + red[3] + red[5] + red[7];
    float mean = s1 * (1.f / 1024.f);
    float var  = s2 * (1.f / 1024.f) - mean * mean;
    float rstd = rsqrtf(var + LN_EPS);
    int d0 = tid * 4;
    pln[d0 + 0] = (v.x - mean) * rstd * g2[d0 + 0] + b2[d0 + 0];
    pln[d0 + 1] = (v.y - mean) * rstd * g2[d0 + 1] + b2[d0 + 1];
    pln[d0 + 2] = (v.z - mean) * rstd * g2[d0 + 2] + b2[d0 + 2];
    pln[d0 + 3] = (v.w - mean) * rstd * g2[d0 + 3] + b2[d0 + 3];
    __syncthreads();
    int q = tid & 15, c = tid >> 4;
    if (c < 14) {
        float s = 0.f;
#pragma unroll 8
        for (int i = 0; i < 64; ++i) {
            int d = i * 16 + q;
            s += pln[d] * Wp[c * DD + d];
        }
#pragma unroll
        for (int m = 1; m < 16; m <<= 1) s += __shfl_xor(s, m, 64);
        if (q == 0) out[b * 14 + c] = s + bp[c];
    }
}

extern "C" void kernel_launch(void* const* d_in, const int* in_sizes, int n_in,
                              void* d_out, int out_size, void* d_ws, size_t ws_size,
                              hipStream_t stream) {
    const float* cls   = (const float*)d_in[0];
    const float* sto   = (const float*)d_in[1];
    const float* pat   = (const float*)d_in[2];
    const float* query = (const float*)d_in[3];
    const float* g     = (const float*)d_in[4];
    const float* bln   = (const float*)d_in[5];
    const float* Wq    = (const float*)d_in[6];
    const float* Wk    = (const float*)d_in[7];
    const float* Wv    = (const float*)d_in[8];
    const float* bq    = (const float*)d_in[9];
    const float* bk    = (const float*)d_in[10];
    const float* bv    = (const float*)d_in[11];
    const float* Wo    = (const float*)d_in[12];
    const float* bo    = (const float*)d_in[13];
    const float* g2    = (const float*)d_in[14];
    const float* b2    = (const float*)d_in[15];
    const float* Wp    = (const float*)d_in[16];
    const float* bp    = (const float*)d_in[17];

    float* ws     = (float*)d_ws;
    float* qvec   = ws + WS_QVEC;
    float* uvec   = ws + WS_U;
    float* cv     = ws + WS_C;
    float* pl     = ws + WS_PL;
    float* ps     = ws + WS_PS;
    float* sbar   = ws + WS_SBAR;
    float* ctx    = ws + WS_CTX;
    float* pooled = ws + WS_POOLED;
    float* out    = (float*)d_out;

    hipLaunchKernelGGL(k_qvec, dim3(1024), dim3(64), 0, stream, query, Wq, bq, qvec);
    hipLaunchKernelGGL(k_u,    dim3(64),   dim3(256), 0, stream, Wk, qvec, uvec);
    hipLaunchKernelGGL(k_c,    dim3(1),    dim3(64), 0, stream, qvec, bk, cv);
    hipLaunchKernelGGL(k_main, dim3(BB * NCH), dim3(256), 0, stream,
                       cls, sto, pat, g, bln, uvec, cv, ps, pl);
    hipLaunchKernelGGL(k_comb, dim3(BB * HH), dim3(256), 0, stream, ps, pl, sbar);
    hipLaunchKernelGGL(k_ctx,  dim3(1024), dim3(256), 0, stream, Wv, bv, sbar, ctx);
    hipLaunchKernelGGL(k_pool, dim3(1024), dim3(256), 0, stream, Wo, bo, ctx, pooled);
    hipLaunchKernelGGL(k_head, dim3(64),   dim3(256), 0, stream, pooled, g2, b2, Wp, bp, out);
}

// Round 4
// 279.174 us; speedup vs baseline: 3.1589x; 3.1589x over previous
//
#include <hip/hip_runtime.h>
#include <hip/hip_bf16.h>

#define BB 64
#define DD 1024
#define HH 16
#define LL 4101          // 1 + 4 + 4096
#define NCH 8
#define CHUNK 513
#define SCALE 0.125f
#define LN_EPS 1e-5f

typedef float  f32x4 __attribute__((ext_vector_type(4)));
typedef short  s16x8 __attribute__((ext_vector_type(8)));
typedef unsigned int u32x4 __attribute__((ext_vector_type(4)));

// workspace layout (float offsets)
#define WS_QVEC 0               // 1024
#define WS_GU   1024            // 16*1024
#define WS_G    17408           // 16
#define WS_BU   17424           // 16
#define WS_CB   17440           // 16
#define WS_PL   17456           // 64*8*16 = 8192
#define WS_PM   25648           // 8192
#define WS_PA   33840           // 64*8*16*1024 = 8388608  (sbar overlays ch=0 slice)
#define WS_CTX  8422448         // 65536
#define WS_POOL 8487984         // 65536

__device__ __forceinline__ unsigned int pk2(float a, float b) {
    __hip_bfloat162 h = __float22bfloat162_rn(make_float2(a, b));
    unsigned int r;
    __builtin_memcpy(&r, &h, 4);
    return r;
}

// ---------------- prep: qp = Wq*query + bq ----------------
__global__ void k_qvec(const float* __restrict__ query, const float* __restrict__ Wq,
                       const float* __restrict__ bq, float* __restrict__ qvec) {
    int j = blockIdx.x; int lane = threadIdx.x;          // 64 threads
    const float4* wr = reinterpret_cast<const float4*>(Wq + (size_t)j * DD);
    const float4* qr = reinterpret_cast<const float4*>(query);
    float s = 0.f;
#pragma unroll
    for (int k = 0; k < 4; ++k) {
        float4 a = wr[k * 64 + lane];
        float4 q = qr[k * 64 + lane];
        s += a.x * q.x + a.y * q.y + a.z * q.z + a.w * q.w;
    }
#pragma unroll
    for (int m = 1; m < 64; m <<= 1) s += __shfl_xor(s, m, 64);
    if (lane == 0) qvec[j] = s + bq[j];
}

// ---------------- prep: gu = g .* (scale*Wk_h^T qp_h), G_h = sum(gu), Bu_h = sum(b.*u) ----------------
__global__ void k_u(const float* __restrict__ Wk, const float* __restrict__ qvec,
                    const float* __restrict__ g, const float* __restrict__ bln,
                    float* __restrict__ gu, float* __restrict__ Gv, float* __restrict__ Bu) {
    int h = blockIdx.x; int tid = threadIdx.x;
    int w = tid >> 6, lane = tid & 63;
    __shared__ float qs[64];
    __shared__ float red[8];
    if (tid < 64) qs[tid] = qvec[h * 64 + tid];
    __syncthreads();
    int d0 = tid * 4;
    float ax = 0.f, ay = 0.f, az = 0.f, aw = 0.f;
    for (int i = 0; i < 64; ++i) {
        float q = qs[i];
        float4 wv = *reinterpret_cast<const float4*>(&Wk[(size_t)(h * 64 + i) * DD + d0]);
        ax += q * wv.x; ay += q * wv.y; az += q * wv.z; aw += q * wv.w;
    }
    float4 g4 = *reinterpret_cast<const float4*>(&g[d0]);
    float4 b4 = *reinterpret_cast<const float4*>(&bln[d0]);
    float ux = ax * SCALE, uy = ay * SCALE, uz = az * SCALE, uw = aw * SCALE;
    float4 gu4 = make_float4(ux * g4.x, uy * g4.y, uz * g4.z, uw * g4.w);
    *reinterpret_cast<float4*>(&gu[(size_t)h * DD + d0]) = gu4;
    float Gp = gu4.x + gu4.y + gu4.z + gu4.w;
    float Bp = ux * b4.x + uy * b4.y + uz * b4.z + uw * b4.w;
#pragma unroll
    for (int m = 1; m < 64; m <<= 1) { Gp += __shfl_xor(Gp, m, 64); Bp += __shfl_xor(Bp, m, 64); }
    if (lane == 0) { red[2 * w] = Gp; red[2 * w + 1] = Bp; }
    __syncthreads();
    if (tid == 0) {
        Gv[h] = red[0] + red[2] + red[4] + red[6];
        Bu[h] = red[1] + red[3] + red[5] + red[7];
    }
}

// ---------------- prep: CB_h = Bu_h + scale*(qp_h . bk_h) ----------------
__global__ void k_cq(const float* __restrict__ qvec, const float* __restrict__ bk,
                     const float* __restrict__ Bu, float* __restrict__ CB) {
    int h = threadIdx.x;
    if (h < HH) {
        float s = 0.f;
        for (int i = 0; i < 64; ++i) s += qvec[h * 64 + i] * bk[h * 64 + i];
        CB[h] = Bu[h] + s * SCALE;
    }
}

// ---------------- fused main pass (MFMA) ----------------
__global__ __launch_bounds__(256, 2) void k_main(
    const float* __restrict__ cls, const float* __restrict__ sto,
    const float* __restrict__ pat, const float* __restrict__ gu,
    const float* __restrict__ Gv, const float* __restrict__ CBv,
    float* __restrict__ pA, float* __restrict__ pl, float* __restrict__ pM) {

    __shared__ __align__(16) ushort Xlds[32 * 1024];   // 64 KB, subtiled [r>>2][d>>4][r&3][d&15]
    __shared__ __align__(16) f32x4 csr[4][2][64];      // 8 KB score partials
    __shared__ __align__(16) ushort alds[512];         // 1 KB  alpha bf16 [16h][32r]
    __shared__ float2 mrs[32];                         // (rstd, -mean*rstd)

    const int blk = blockIdx.x;
    const int b = blk >> 3, ch = blk & 7;
    const int row0 = ch * CHUNK;
    const int rows = min(CHUNK, LL - row0);
    const int nt = (rows + 31) >> 5;
    const int tid = threadIdx.x;
    const int w = tid >> 6, lane = tid & 63;
    const int lm = lane & 15, lg = lane >> 4;

    // preload gu B-fragments: head=lm, d = w*256 + s*32 + lg*8 + j
    s16x8 guf[8];
    {
        const float* gubase = gu + (size_t)lm * DD + w * 256 + lg * 8;
#pragma unroll
        for (int s = 0; s < 8; ++s) {
            const float* p = gubase + s * 32;
            u32x4 t;
#pragma unroll
            for (int j = 0; j < 4; ++j) t[j] = pk2(p[2 * j], p[2 * j + 1]);
            guf[s] = __builtin_bit_cast(s16x8, t);
        }
    }
    const float Gh = Gv[lm], CBh = CBv[lm];

    f32x4 acc[16];
#pragma unroll
    for (int i = 0; i < 16; ++i) acc[i] = (f32x4){0.f, 0.f, 0.f, 0.f};
    float lacc = 0.f, macc = 0.f;

    // per-lane constants (element indices into Xlds)
    const int C0 = (lm >> 2) * 4096 + w * 1024 + (lg >> 1) * 64 + (lm & 3) * 16 + (lg & 1) * 8;
    const int bbase = lg * 8192 + w * 1024 + lm;   // op4 B-frag base: r=8lg, d=w*256+lm
    const int aoff = lm * 32 + lg * 8;

    for (int t = 0; t < nt; ++t) {
        // ---- stage: fp32->bf16 into subtiled Xlds + LN stats ----
#pragma unroll 2
        for (int rr = 0; rr < 8; ++rr) {
            int rl = w * 8 + rr;
            int rloc = t * 32 + rl;
            bool valid = rloc < rows;
            float4 v[4];
            if (valid) {
                int gr = row0 + rloc;
                const float* src;
                if (gr == 0)      src = cls + (size_t)b * DD;
                else if (gr <= 4) src = sto + ((size_t)b * 4 + (gr - 1)) * DD;
                else              src = pat + ((size_t)b * 4096 + (gr - 5)) * DD;
                const float4* s4 = reinterpret_cast<const float4*>(src);
#pragma unroll
                for (int it = 0; it < 4; ++it) v[it] = s4[it * 64 + lane];
            } else {
#pragma unroll
                for (int it = 0; it < 4; ++it) v[it] = make_float4(0.f, 0.f, 0.f, 0.f);
            }
            float s1 = 0.f, s2 = 0.f;
#pragma unroll
            for (int it = 0; it < 4; ++it) {
                float4 q = v[it];
                s1 += q.x + q.y + q.z + q.w;
                s2 += q.x * q.x + q.y * q.y + q.z * q.z + q.w * q.w;
                uint2 pk;
                pk.x = pk2(q.x, q.y);
                pk.y = pk2(q.z, q.w);
                int d0 = 4 * (it * 64 + lane);
                int elem = ((rl >> 2) * 64 + (d0 >> 4)) * 64 + ((rl & 3) << 4) + (d0 & 15);
                *reinterpret_cast<uint2*>(&Xlds[elem]) = pk;
            }
#pragma unroll
            for (int m = 1; m < 64; m <<= 1) {
                s1 += __shfl_xor(s1, m, 64);
                s2 += __shfl_xor(s2, m, 64);
            }
            if (lane == 0) {
                float mean = s1 * (1.f / 1024.f);
                float var = s2 * (1.f / 1024.f) - mean * mean;
                float rstd = rsqrtf(var + LN_EPS);
                mrs[rl] = make_float2(rstd, -mean * rstd);
            }
        }
        __syncthreads();

        // ---- op2: score dot partials ----
        {
            f32x4 c0 = {0.f, 0.f, 0.f, 0.f}, c1 = {0.f, 0.f, 0.f, 0.f};
#pragma unroll
            for (int s = 0; s < 8; ++s) {
                s16x8 a0 = *reinterpret_cast<const s16x8*>(&Xlds[C0 + s * 128]);
                s16x8 a1 = *reinterpret_cast<const s16x8*>(&Xlds[C0 + 16384 + s * 128]);
                c0 = __builtin_amdgcn_mfma_f32_16x16x32_bf16(a0, guf[s], c0, 0, 0, 0);
                c1 = __builtin_amdgcn_mfma_f32_16x16x32_bf16(a1, guf[s], c1, 0, 0, 0);
            }
            csr[w][0][lane] = c0;
            csr[w][1][lane] = c1;
        }
        __syncthreads();

        // ---- finalize (wave 0 only) ----
        if (w == 0) {
            f32x4 d0v = csr[0][0][lane], d1v = csr[0][1][lane];
#pragma unroll
            for (int wp = 1; wp < 4; ++wp) {
                f32x4 e0 = csr[wp][0][lane], e1 = csr[wp][1][lane];
                d0v += e0; d1v += e1;
            }
#pragma unroll
            for (int tt = 0; tt < 2; ++tt) {
                f32x4 dv = tt ? d1v : d0v;
                int rbase = tt * 16 + lg * 4;
                float al[4];
#pragma unroll
                for (int i = 0; i < 4; ++i) {
                    float2 mr = mrs[rbase + i];
                    float sc = dv[i] * mr.x + (mr.y * Gh + CBh);
                    bool vld = (t * 32 + rbase + i) < rows;
                    float p = vld ? __expf(sc) : 0.f;
                    lacc += p;
                    macc += p * mr.y;          // = -sum(p*mean*rstd)
                    al[i] = p * mr.x;          // alpha
                }
                unsigned int q0 = pk2(al[0], al[1]);
                unsigned int q1 = pk2(al[2], al[3]);
                *reinterpret_cast<unsigned int*>(&alds[lm * 32 + rbase])     = q0;
                *reinterpret_cast<unsigned int*>(&alds[lm * 32 + rbase + 2]) = q1;
            }
        }
        __syncthreads();

        // ---- op4: acc[h][d] += alpha^T . X  (B-frags via scalar LDS reads) ----
        {
            s16x8 af = *reinterpret_cast<const s16x8*>(&alds[aoff]);
#pragma unroll
            for (int dt = 0; dt < 16; ++dt) {
                s16x8 bfrag;
#pragma unroll
                for (int j = 0; j < 8; ++j) {
                    // r = 8*lg + j, d = w*256 + dt*16 + lm
                    int e = bbase + dt * 64 + ((j & 3) << 4) + ((j >> 2) << 12);
                    bfrag[j] = (short)Xlds[e];
                }
                acc[dt] = __builtin_amdgcn_mfma_f32_16x16x32_bf16(af, bfrag, acc[dt], 0, 0, 0);
            }
        }
        __syncthreads();
    }

    // write partial A  (pA[blk][h][1024])
    size_t pabase = ((size_t)blk << 14);
#pragma unroll
    for (int dt = 0; dt < 16; ++dt) {
#pragma unroll
        for (int i = 0; i < 4; ++i) {
            int h = lg * 4 + i;
            pA[pabase + ((size_t)h << 10) + w * 256 + dt * 16 + lm] = acc[dt][i];
        }
    }
    if (w == 0) {
        lacc += __shfl_xor(lacc, 16, 64); lacc += __shfl_xor(lacc, 32, 64);
        macc += __shfl_xor(macc, 16, 64); macc += __shfl_xor(macc, 32, 64);
        if (lane < 16) {
            pl[blk * 16 + lane] = lacc;
            pM[blk * 16 + lane] = -macc;       // = sum(p*mean*rstd)
        }
    }
}

// ---------------- combine partials: sbar = (g.*(A - M))/l + b  (overlays pA ch=0) ----------------
__global__ void k_comb(float* __restrict__ pA, const float* __restrict__ pl,
                       const float* __restrict__ pM, const float* __restrict__ g,
                       const float* __restrict__ bln) {
    int blk = blockIdx.x; int b = blk >> 4; int h = blk & 15; int tid = threadIdx.x;
    float l = 0.f, M = 0.f;
#pragma unroll
    for (int ch = 0; ch < NCH; ++ch) {
        l += pl[(b * NCH + ch) * 16 + h];
        M += pM[(b * NCH + ch) * 16 + h];
    }
    float inv = 1.f / l;
    float4 s = make_float4(0.f, 0.f, 0.f, 0.f);
#pragma unroll
    for (int ch = 0; ch < NCH; ++ch) {
        const float4* p4 = reinterpret_cast<const float4*>(
            pA + (((size_t)(b * NCH + ch) * 16 + h) << 10));
        float4 v = p4[tid];
        s.x += v.x; s.y += v.y; s.z += v.z; s.w += v.w;
    }
    float4 g4 = *reinterpret_cast<const float4*>(&g[tid * 4]);
    float4 b4 = *reinterpret_cast<const float4*>(&bln[tid * 4]);
    float4 o;
    o.x = g4.x * (s.x - M) * inv + b4.x;
    o.y = g4.y * (s.y - M) * inv + b4.y;
    o.z = g4.z * (s.z - M) * inv + b4.z;
    o.w = g4.w * (s.w - M) * inv + b4.w;
    float4* dst = reinterpret_cast<float4*>(pA + (((size_t)(b * NCH) * 16 + h) << 10));
    dst[tid] = o;
}

// ---------------- ctx = Wv_h * sbar_h + bv ----------------
__global__ void k_ctx(const float* __restrict__ Wv, const float* __restrict__ bv,
                      const float* __restrict__ pA, float* __restrict__ ctx) {
    int j = blockIdx.x; int h = j >> 6;
    int w = threadIdx.x >> 6, lane = threadIdx.x & 63;
    const float4* wr = reinterpret_cast<const float4*>(Wv + (size_t)j * DD);
    float4 wv[4];
#pragma unroll
    for (int k = 0; k < 4; ++k) wv[k] = wr[k * 64 + lane];
    float bvj = bv[j];
    for (int bb2 = w * 16; bb2 < w * 16 + 16; ++bb2) {
        const float4* sr = reinterpret_cast<const float4*>(
            pA + (((size_t)(bb2 * NCH) * 16 + h) << 10));
        float s = 0.f;
#pragma unroll
        for (int k = 0; k < 4; ++k) {
            float4 v = sr[k * 64 + lane];
            s += wv[k].x * v.x + wv[k].y * v.y + wv[k].z * v.z + wv[k].w * v.w;
        }
#pragma unroll
        for (int m = 1; m < 64; m <<= 1) s += __shfl_xor(s, m, 64);
        if (lane == 0) ctx[(size_t)bb2 * DD + j] = s + bvj;
    }
}

// ---------------- pooled = Wo * ctx + bo ----------------
__global__ void k_pool(const float* __restrict__ Wo, const float* __restrict__ bo,
                       const float* __restrict__ ctx, float* __restrict__ pooled) {
    int j = blockIdx.x;
    int w = threadIdx.x >> 6, lane = threadIdx.x & 63;
    const float4* wr = reinterpret_cast<const float4*>(Wo + (size_t)j * DD);
    float4 wv[4];
#pragma unroll
    for (int k = 0; k < 4; ++k) wv[k] = wr[k * 64 + lane];
    float boj = bo[j];
    for (int bb2 = w * 16; bb2 < w * 16 + 16; ++bb2) {
        const float4* cr4 = reinterpret_cast<const float4*>(ctx + (size_t)bb2 * DD);
        float s = 0.f;
#pragma unroll
        for (int k = 0; k < 4; ++k) {
            float4 v = cr4[k * 64 + lane];
            s += wv[k].x * v.x + wv[k].y * v.y + wv[k].z * v.z + wv[k].w * v.w;
        }
#pragma unroll
        for (int m = 1; m < 64; m <<= 1) s += __shfl_xor(s, m, 64);
        if (lane == 0) pooled[(size_t)bb2 * DD + j] = s + boj;
    }
}

// ---------------- final LN + classifier head ----------------
__global__ void k_head(const float* __restrict__ pooled, const float* __restrict__ g2,
                       const float* __restrict__ b2, const float* __restrict__ Wp,
                       const float* __restrict__ bp, float* __restrict__ out) {
    int b = blockIdx.x; int tid = threadIdx.x;
    __shared__ float pln[DD];
    __shared__ float red[8];
    const float4* pr = reinterpret_cast<const float4*>(pooled + (size_t)b * DD);
    float4 v = pr[tid];
    float s1 = v.x + v.y + v.z + v.w;
    float s2 = v.x * v.x + v.y * v.y + v.z * v.z + v.w * v.w;
#pragma unroll
    for (int m = 1; m < 64; m <<= 1) { s1 += __shfl_xor(s1, m, 64); s2 += __shfl_xor(s2, m, 64); }
    int w = tid >> 6, lane = tid & 63;
    if (lane == 0) { red[2 * w] = s1; red[2 * w + 1] = s2; }
    __syncthreads();
    s1 = red[0] + red[2] + red[4] + red[6];
    s2 = red[1] + red[3] + red[5] + red[7];
    float mean = s1 * (1.f / 1024.f);
    float var  = s2 * (1.f / 1024.f) - mean * mean;
    float rstd = rsqrtf(var + LN_EPS);
    int d0 = tid * 4;
    pln[d0 + 0] = (v.x - mean) * rstd * g2[d0 + 0] + b2[d0 + 0];
    pln[d0 + 1] = (v.y - mean) * rstd * g2[d0 + 1] + b2[d0 + 1];
    pln[d0 + 2] = (v.z - mean) * rstd * g2[d0 + 2] + b2[d0 + 2];
    pln[d0 + 3] = (v.w - mean) * rstd * g2[d0 + 3] + b2[d0 + 3];
    __syncthreads();
    int q = tid & 15, c = tid >> 4;
    if (c < 14) {
        float s = 0.f;
#pragma unroll 8
        for (int i = 0; i < 64; ++i) {
            int d = i * 16 + q;
            s += pln[d] * Wp[c * DD + d];
        }
#pragma unroll
        for (int m = 1; m < 16; m <<= 1) s += __shfl_xor(s, m, 64);
        if (q == 0) out[b * 14 + c] = s + bp[c];
    }
}

extern "C" void kernel_launch(void* const* d_in, const int* in_sizes, int n_in,
                              void* d_out, int out_size, void* d_ws, size_t ws_size,
                              hipStream_t stream) {
    const float* cls   = (const float*)d_in[0];
    const float* sto   = (const float*)d_in[1];
    const float* pat   = (const float*)d_in[2];
    const float* query = (const float*)d_in[3];
    const float* g     = (const float*)d_in[4];
    const float* bln   = (const float*)d_in[5];
    const float* Wq    = (const float*)d_in[6];
    const float* Wk    = (const float*)d_in[7];
    const float* Wv    = (const float*)d_in[8];
    const float* bq    = (const float*)d_in[9];
    const float* bk    = (const float*)d_in[10];
    const float* bv    = (const float*)d_in[11];
    const float* Wo    = (const float*)d_in[12];
    const float* bo    = (const float*)d_in[13];
    const float* g2    = (const float*)d_in[14];
    const float* b2    = (const float*)d_in[15];
    const float* Wp    = (const float*)d_in[16];
    const float* bp    = (const float*)d_in[17];

    float* ws     = (float*)d_ws;
    float* qvec   = ws + WS_QVEC;
    float* gu     = ws + WS_GU;
    float* Gv     = ws + WS_G;
    float* Bu     = ws + WS_BU;
    float* CB     = ws + WS_CB;
    float* pl     = ws + WS_PL;
    float* pM     = ws + WS_PM;
    float* pA     = ws + WS_PA;
    float* ctx    = ws + WS_CTX;
    float* pooled = ws + WS_POOL;
    float* out    = (float*)d_out;

    hipLaunchKernelGGL(k_qvec, dim3(1024), dim3(64), 0, stream, query, Wq, bq, qvec);
    hipLaunchKernelGGL(k_u,    dim3(16),   dim3(256), 0, stream, Wk, qvec, g, bln, gu, Gv, Bu);
    hipLaunchKernelGGL(k_cq,   dim3(1),    dim3(64), 0, stream, qvec, bk, Bu, CB);
    hipLaunchKernelGGL(k_main, dim3(BB * NCH), dim3(256), 0, stream,
                       cls, sto, pat, gu, Gv, CB, pA, pl, pM);
    hipLaunchKernelGGL(k_comb, dim3(BB * HH), dim3(256), 0, stream, pA, pl, pM, g, bln);
    hipLaunchKernelGGL(k_ctx,  dim3(1024), dim3(256), 0, stream, Wv, bv, pA, ctx);
    hipLaunchKernelGGL(k_pool, dim3(1024), dim3(256), 0, stream, Wo, bo, ctx, pooled);
    hipLaunchKernelGGL(k_head, dim3(64),   dim3(256), 0, stream, pooled, g2, b2, Wp, bp, out);
}